// Round 17
// baseline (116.668 us; speedup 1.0000x reference)
//
#include <hip/hip_runtime.h>
#include <cstddef>

typedef __attribute__((ext_vector_type(4))) float f32x4;
typedef __attribute__((ext_vector_type(16))) float f32x16;
typedef __attribute__((ext_vector_type(8))) short bf16x8;

#define MFMA16(A, B, C) __builtin_amdgcn_mfma_f32_16x16x32_bf16(A, B, C, 0, 0, 0)
#define MFMA32(A, B, C) __builtin_amdgcn_mfma_f32_32x32x16_bf16(A, B, C, 0, 0, 0)

__device__ __forceinline__ unsigned short f2bf(float f) {
  unsigned u = __float_as_uint(f);
  u += 0x7fffu + ((u >> 16) & 1u);
  return (unsigned short)(u >> 16);
}
__device__ __forceinline__ float bf2f(unsigned short s) {
  return __uint_as_float(((unsigned)s) << 16);
}

__device__ __forceinline__ void cvt_split8(float4 a, float4 b, bf16x8* H, bf16x8* L) {
  float v[8] = {a.x, a.y, a.z, a.w, b.x, b.y, b.z, b.w};
  unsigned hh[4], ll[4];
  #pragma unroll
  for (int p = 0; p < 4; ++p) {
    unsigned short h0 = f2bf(v[2 * p]), h1 = f2bf(v[2 * p + 1]);
    hh[p] = (unsigned)h0 | ((unsigned)h1 << 16);
    unsigned short l0 = f2bf(v[2 * p] - bf2f(h0));
    unsigned short l1 = f2bf(v[2 * p + 1] - bf2f(h1));
    ll[p] = (unsigned)l0 | ((unsigned)l1 << 16);
  }
  uint4 uh; uh.x = hh[0]; uh.y = hh[1]; uh.z = hh[2]; uh.w = hh[3];
  uint4 ul; ul.x = ll[0]; ul.y = ll[1]; ul.z = ll[2]; ul.w = ll[3];
  *H = *(bf16x8*)&uh;
  *L = *(bf16x8*)&ul;
}

__device__ __forceinline__ bf16x8 cvt_hi8(float4 a, float4 b) {
  float v[8] = {a.x, a.y, a.z, a.w, b.x, b.y, b.z, b.w};
  unsigned hh[4];
  #pragma unroll
  for (int p = 0; p < 4; ++p)
    hh[p] = (unsigned)f2bf(v[2 * p]) | ((unsigned)f2bf(v[2 * p + 1]) << 16);
  uint4 uh; uh.x = hh[0]; uh.y = hh[1]; uh.z = hh[2]; uh.w = hh[3];
  return *(bf16x8*)&uh;
}

// ---------- weight prep: fragment-major (FM) ----------

__global__ void prep_k(const float* __restrict__ Wf, const float* __restrict__ Wg,
                       const float* __restrict__ Wh, const float* __restrict__ Wv,
                       unsigned short* __restrict__ wfh, unsigned short* __restrict__ wfl,
                       unsigned short* __restrict__ wgh, unsigned short* __restrict__ wgl,
                       unsigned short* __restrict__ whb, unsigned short* __restrict__ wvb) {
  int i = blockIdx.x * 256 + threadIdx.x;
  if (i < 65536) {
    int ii = i & 32767;
    int j = ii & 7, slot = (ii >> 3) & 63, q = slot & 15, qt2 = slot >> 4;
    int kt = (ii >> 9) & 15, oct = ii >> 13;
    const float* src = (i < 32768) ? Wf : Wg;
    unsigned short* dh = (i < 32768) ? wfh : wgh;
    unsigned short* dl = (i < 32768) ? wfl : wgl;
    float v = src[(oct * 16 + q) * 512 + kt * 32 + qt2 * 8 + j];
    unsigned short h = f2bf(v);
    dh[ii] = h; dl[ii] = f2bf(v - bf2f(h));
  } else if (i < 196608) {
    int ii = i - 65536;
    int j = ii & 7, slot = (ii >> 3) & 63, q = slot & 15, qt2 = slot >> 4;
    int kt = (ii >> 9) & 15, oct = ii >> 13;
    whb[ii] = f2bf(Wh[(oct * 16 + q) * 512 + kt * 32 + qt2 * 8 + j]);
  } else if (i < 327680) {
    int ii = i - 196608;
    int j = ii & 7, slot = (ii >> 3) & 63, q = slot & 15, qt2 = slot >> 4;
    int kt = (ii >> 9) & 7, oct = ii >> 12;
    wvb[ii] = f2bf(Wv[(oct * 16 + q) * 256 + kt * 32 + qt2 * 8 + j]);
  }
}

// ---------- conv_all: global_load_lds staging (k-major fp32 LDS), 2 roles, XCD-local b ----------

#define STAGE(BUF, CN) { _Pragma("unroll") \
  for (int c_ = 0; c_ < 8; ++c_) { \
    __builtin_amdgcn_global_load_lds( \
      (const __attribute__((address_space(1))) unsigned int*)(xg + (size_t)((CN) * 64 + c_ * 2) * 4096), \
      (__attribute__((address_space(3))) unsigned int*)(&xs[BUF][w * 16 + c_ * 2][0]), \
      16, 0, 0); } }

__global__ __launch_bounds__(256, 2)
void conv_all(const float* __restrict__ x,
              const unsigned short* __restrict__ wfh_, const unsigned short* __restrict__ wfl_,
              const unsigned short* __restrict__ wgh_, const unsigned short* __restrict__ wgl_,
              const unsigned short* __restrict__ whb_,
              const float* __restrict__ bf_, const float* __restrict__ bg_,
              const float* __restrict__ bh_,
              unsigned short* __restrict__ fhi, unsigned short* __restrict__ flo,
              unsigned short* __restrict__ ghi, unsigned short* __restrict__ glo,
              unsigned short* __restrict__ vp)
{
  __shared__ __align__(16) float xs[2][64][128];    // 65,536 B, k-major
  const int bid = blockIdx.x;
  const int b = bid & 7;
  const int idx = bid >> 3;
  const int role = idx & 1;
  const int hp = idx >> 1;
  const int n0 = hp * 128;
  const int tid = threadIdx.x, w = tid >> 6, lane = tid & 63, q = lane & 15, qt = lane >> 4;
  const float* xg = x + ((size_t)(b * 512 + w * 16 + (lane >> 5)) * 4096) + n0 + (lane & 31) * 4;

  if (role == 0) {
    f32x4 accf[2][4], accg[2][4];
    #pragma unroll
    for (int nt = 0; nt < 2; ++nt)
      #pragma unroll
      for (int ot = 0; ot < 4; ++ot) {
        accf[nt][ot] = (f32x4){0.f, 0.f, 0.f, 0.f};
        accg[nt][ot] = (f32x4){0.f, 0.f, 0.f, 0.f};
      }
    STAGE(0, 0)
    __syncthreads();
    for (int cc = 0; cc < 8; ++cc) {
      const int cur = cc & 1;
      if (cc < 7) STAGE(cur ^ 1, cc + 1)
      #pragma unroll
      for (int kh = 0; kh < 2; ++kh) {
        const int kt = cc * 2 + kh;
        bf16x8 Ah[2], Al[2];
        #pragma unroll
        for (int nt = 0; nt < 2; ++nt) {
          const int row = w * 32 + nt * 16 + q;
          float xv[8];
          #pragma unroll
          for (int j = 0; j < 8; ++j)
            xv[j] = xs[cur][kh * 32 + qt * 8 + j][row];
          float4 a0; a0.x = xv[0]; a0.y = xv[1]; a0.z = xv[2]; a0.w = xv[3];
          float4 a1; a1.x = xv[4]; a1.y = xv[5]; a1.z = xv[6]; a1.w = xv[7];
          cvt_split8(a0, a1, &Ah[nt], &Al[nt]);
        }
        {
          bf16x8 Bh[4], Bl[4];
          #pragma unroll
          for (int ot = 0; ot < 4; ++ot) {
            size_t wb = ((size_t)(ot * 16 + kt) << 9) + lane * 8;
            Bh[ot] = *(const bf16x8*)(wfh_ + wb);
            Bl[ot] = *(const bf16x8*)(wfl_ + wb);
          }
          #pragma unroll
          for (int nt = 0; nt < 2; ++nt)
            #pragma unroll
            for (int ot = 0; ot < 4; ++ot) {
              accf[nt][ot] = MFMA16(Ah[nt], Bh[ot], accf[nt][ot]);
              accf[nt][ot] = MFMA16(Ah[nt], Bl[ot], accf[nt][ot]);
              accf[nt][ot] = MFMA16(Al[nt], Bh[ot], accf[nt][ot]);
            }
        }
        {
          bf16x8 Bh[4], Bl[4];
          #pragma unroll
          for (int ot = 0; ot < 4; ++ot) {
            size_t wb = ((size_t)(ot * 16 + kt) << 9) + lane * 8;
            Bh[ot] = *(const bf16x8*)(wgh_ + wb);
            Bl[ot] = *(const bf16x8*)(wgl_ + wb);
          }
          #pragma unroll
          for (int nt = 0; nt < 2; ++nt)
            #pragma unroll
            for (int ot = 0; ot < 4; ++ot) {
              accg[nt][ot] = MFMA16(Ah[nt], Bh[ot], accg[nt][ot]);
              accg[nt][ot] = MFMA16(Ah[nt], Bl[ot], accg[nt][ot]);
              accg[nt][ot] = MFMA16(Al[nt], Bh[ot], accg[nt][ot]);
            }
        }
      }
      __syncthreads();
    }
    #pragma unroll
    for (int nt = 0; nt < 2; ++nt)
      #pragma unroll
      for (int ot = 0; ot < 4; ++ot)
        #pragma unroll
        for (int r = 0; r < 4; ++r) {
          float v = accf[nt][ot][r] + bf_[ot * 16 + q];
          unsigned short h = f2bf(v);
          size_t o = (((size_t)(b * 128 + hp * 4 + w) * 4 + ot) * 64 +
                      (q >> 3) * 32 + nt * 16 + qt * 4 + r) * 8 + (q & 7);
          fhi[o] = h;
          flo[o] = f2bf(v - bf2f(h));
        }
    float (*pl)[67] = (float(*)[67])&xs[0][0][0];
    #pragma unroll
    for (int nt = 0; nt < 2; ++nt)
      #pragma unroll
      for (int ot = 0; ot < 4; ++ot)
        #pragma unroll
        for (int r = 0; r < 4; ++r)
          pl[w * 32 + nt * 16 + qt * 4 + r][ot * 16 + q] = accg[nt][ot][r];
    __syncthreads();
    const int c = tid & 63;
    #pragma unroll
    for (int it = 0; it < 8; ++it) {
      int wp = (tid >> 6) + it * 4;
      float v = fmaxf(fmaxf(pl[2 * wp][c], pl[2 * wp + 1][c]),
                      fmaxf(pl[64 + 2 * wp][c], pl[65 + 2 * wp][c])) + bg_[c];
      unsigned short h = f2bf(v);
      size_t o = (((size_t)(b * 32 + hp) * 4 + (c >> 4)) * 64 +
                  ((c >> 3) & 1) * 32 + wp) * 8 + (c & 7);
      ghi[o] = h;
      glo[o] = f2bf(v - bf2f(h));
    }
  } else {
    f32x4 acc[2][16];
    #pragma unroll
    for (int nt = 0; nt < 2; ++nt)
      #pragma unroll
      for (int ot = 0; ot < 16; ++ot) acc[nt][ot] = (f32x4){0.f, 0.f, 0.f, 0.f};
    STAGE(0, 0)
    __syncthreads();
    for (int cc = 0; cc < 8; ++cc) {
      const int cur = cc & 1;
      if (cc < 7) STAGE(cur ^ 1, cc + 1)
      #pragma unroll
      for (int kh = 0; kh < 2; ++kh) {
        const int kt = cc * 2 + kh;
        bf16x8 A_[2];
        #pragma unroll
        for (int nt = 0; nt < 2; ++nt) {
          const int row = w * 32 + nt * 16 + q;
          float xv[8];
          #pragma unroll
          for (int j = 0; j < 8; ++j)
            xv[j] = xs[cur][kh * 32 + qt * 8 + j][row];
          float4 a0; a0.x = xv[0]; a0.y = xv[1]; a0.z = xv[2]; a0.w = xv[3];
          float4 a1; a1.x = xv[4]; a1.y = xv[5]; a1.z = xv[6]; a1.w = xv[7];
          A_[nt] = cvt_hi8(a0, a1);
        }
        #pragma unroll
        for (int oh = 0; oh < 2; ++oh) {
          bf16x8 B_[8];
          #pragma unroll
          for (int ot = 0; ot < 8; ++ot)
            B_[ot] = *(const bf16x8*)(whb_ + ((size_t)((oh * 8 + ot) * 16 + kt) << 9) + lane * 8);
          #pragma unroll
          for (int nt = 0; nt < 2; ++nt)
            #pragma unroll
            for (int ot = 0; ot < 8; ++ot)
              acc[nt][oh * 8 + ot] = MFMA16(A_[nt], B_[ot], acc[nt][oh * 8 + ot]);
        }
      }
      __syncthreads();
    }
    float (*pl)[67] = (float(*)[67])&xs[0][0][0];
    #pragma unroll
    for (int oh = 0; oh < 4; ++oh) {
      if (oh) __syncthreads();
      #pragma unroll
      for (int nt = 0; nt < 2; ++nt)
        #pragma unroll
        for (int ot4 = 0; ot4 < 4; ++ot4)
          #pragma unroll
          for (int r = 0; r < 4; ++r)
            pl[w * 32 + nt * 16 + qt * 4 + r][ot4 * 16 + q] = acc[nt][oh * 4 + ot4][r];
      __syncthreads();
      const int wp = tid & 31;
      #pragma unroll
      for (int it = 0; it < 8; ++it) {
        int cc2 = (tid >> 5) + it * 8;
        int cv = oh * 64 + cc2;
        float v = fmaxf(fmaxf(pl[2 * wp][cc2], pl[2 * wp + 1][cc2]),
                        fmaxf(pl[64 + 2 * wp][cc2], pl[65 + 2 * wp][cc2])) + bh_[cv];
        size_t o = (((size_t)(b * 16 + (cv >> 4)) * 32 + hp) * 64 +
                    (wp >> 3) * 16 + (cv & 15)) * 8 + (wp & 7);
        vp[o] = f2bf(v);
      }
    }
  }
}

// ---------- fused attention: QB=32, 4 m-chunks, per-thread (M,S), grid 1024 (4 blocks/CU) ----------

#define PROW 264

__global__ __launch_bounds__(256, 3)
void attn_mfma(const unsigned short* __restrict__ f_, const unsigned short* __restrict__ fl_,
               const unsigned short* __restrict__ g_, const unsigned short* __restrict__ gl_,
               const unsigned short* __restrict__ vp, unsigned short* __restrict__ oT)
{
  __shared__ __align__(16) unsigned short PB[32 * PROW];    // 16,896 B (P, then obuf)
  __shared__ float redm[4][32], reds[4][32];
  const int b = blockIdx.x & 7, bx = blockIdx.x >> 3;       // bx 0..127, 32-q tile
  const int tid = threadIdx.x, w = tid >> 6, lane = tid & 63;
  const int q32 = lane & 31, hl = lane >> 5;
  const int q16 = lane & 15, qt = lane >> 4;

  bf16x8 Fh[4], Fl[4];
  {
    size_t fb = ((size_t)(b * 128 + bx) << 11) + lane * 8;
    #pragma unroll
    for (int s = 0; s < 4; ++s) {
      Fh[s] = *(const bf16x8*)(f_ + fb + (s << 9));
      Fl[s] = *(const bf16x8*)(fl_ + fb + (s << 9));
    }
  }

  float M0 = -3.0e38f;
  float Mp[2], Sp[2];
  #pragma unroll
  for (int qs = 0; qs < 2; ++qs) { Mp[qs] = -3.0e38f; Sp[qs] = 0.f; }
  f32x4 oacc[4][2];       // [c4][qsub: q16, 16+q16]
  #pragma unroll
  for (int c4 = 0; c4 < 4; ++c4)
    #pragma unroll
    for (int qs = 0; qs < 2; ++qs) oacc[c4][qs] = (f32x4){0.f, 0.f, 0.f, 0.f};
  const size_t vroot = ((size_t)(b * 16 + w * 4) * 32) * 512 + lane * 8;

#define VLD(C4, KS) (*(const bf16x8*)(vp + vroot + ((size_t)((C4) * 32 + mc * 8 + (KS)) << 9)))
#define LOADVA(KS) { va0 = VLD(0, KS); va1 = VLD(1, KS); va2 = VLD(2, KS); va3 = VLD(3, KS); }
#define LOADVB(KS) { vb0 = VLD(0, KS); vb1 = VLD(1, KS); vb2 = VLD(2, KS); vb3 = VLD(3, KS); }
#define PVMFMA(KS, V0, V1, V2, V3) { \
  bf16x8 pb0 = *(const bf16x8*)&PB[q16 * PROW + (KS) * 32 + qt * 8]; \
  bf16x8 pb1 = *(const bf16x8*)&PB[(16 + q16) * PROW + (KS) * 32 + qt * 8]; \
  oacc[0][0] = MFMA16(V0, pb0, oacc[0][0]); oacc[1][0] = MFMA16(V1, pb0, oacc[1][0]); \
  oacc[2][0] = MFMA16(V2, pb0, oacc[2][0]); oacc[3][0] = MFMA16(V3, pb0, oacc[3][0]); \
  oacc[0][1] = MFMA16(V0, pb1, oacc[0][1]); oacc[1][1] = MFMA16(V1, pb1, oacc[1][1]); \
  oacc[2][1] = MFMA16(V2, pb1, oacc[2][1]); oacc[3][1] = MFMA16(V3, pb1, oacc[3][1]); }

  #pragma unroll 1
  for (int mc = 0; mc < 4; ++mc) {
    // ---- s phase: wave owns 2 m-tiles of 32 ----
    f32x16 sat0 = {}, sat1 = {};
    __builtin_amdgcn_s_setprio(1);
    #pragma unroll
    for (int t = 0; t < 2; ++t) {
      size_t gb = ((size_t)(b * 32 + mc * 8 + w * 2 + t) << 11) + lane * 8;
      bf16x8 Gh[4], Gl[4];
      #pragma unroll
      for (int s = 0; s < 4; ++s) {
        Gh[s] = *(const bf16x8*)(g_ + gb + (s << 9));
        Gl[s] = *(const bf16x8*)(gl_ + gb + (s << 9));
      }
      f32x16* s0 = t ? &sat1 : &sat0;
      #pragma unroll
      for (int s = 0; s < 4; ++s) {
        *s0 = MFMA32(Gh[s], Fh[s], *s0);
        *s0 = MFMA32(Gh[s], Fl[s], *s0);
        *s0 = MFMA32(Gl[s], Fh[s], *s0);
      }
    }
    __builtin_amdgcn_s_setprio(0);

    bf16x8 va0, va1, va2, va3, vb0, vb1, vb2, vb3;
    LOADVA(0)   // hoisted: independent of softmax

    // ---- online softmax ----
    float mx0 = -3.0e38f;
    #pragma unroll
    for (int r = 0; r < 16; ++r)
      mx0 = fmaxf(mx0, fmaxf(sat0[r], sat1[r]));
    mx0 = fmaxf(mx0, __shfl_xor(mx0, 32));
    if (lane < 32) redm[w][lane] = mx0;
    __syncthreads();                                         // barrier A
    float gmx0 = fmaxf(fmaxf(redm[0][q32], redm[1][q32]), fmaxf(redm[2][q32], redm[3][q32]));
    float Mn0 = fmaxf(M0, gmx0);
    M0 = Mn0;

    float rfp[2];
    #pragma unroll
    for (int qs = 0; qs < 2; ++qs) {
      int cq = qs * 16 + q16;
      float gm = fmaxf(fmaxf(redm[0][cq], redm[1][cq]),
                       fmaxf(redm[2][cq], redm[3][cq]));
      float Mn = fmaxf(Mp[qs], gm);
      rfp[qs] = __expf(Mp[qs] - Mn);
      Mp[qs] = Mn;
    }

    float cs0 = 0.f;
    #pragma unroll
    for (int r = 0; r < 16; ++r) {
      float p;
      p = __expf(sat0[r] - Mn0); sat0[r] = p; cs0 += p;
      p = __expf(sat1[r] - Mn0); sat1[r] = p; cs0 += p;
    }
    cs0 += __shfl_xor(cs0, 32);
    if (lane < 32) reds[w][lane] = cs0;

    #pragma unroll
    for (int j = 0; j < 4; ++j) {
      uint2 pk;
      pk.x = (unsigned)f2bf(sat0[4*j+0]) | ((unsigned)f2bf(sat0[4*j+1]) << 16);
      pk.y = (unsigned)f2bf(sat0[4*j+2]) | ((unsigned)f2bf(sat0[4*j+3]) << 16);
      *(uint2*)&PB[q32 * PROW + w * 64 + j * 8 + hl * 4] = pk;
      pk.x = (unsigned)f2bf(sat1[4*j+0]) | ((unsigned)f2bf(sat1[4*j+1]) << 16);
      pk.y = (unsigned)f2bf(sat1[4*j+2]) | ((unsigned)f2bf(sat1[4*j+3]) << 16);
      *(uint2*)&PB[q32 * PROW + w * 64 + 32 + j * 8 + hl * 4] = pk;
    }
    __syncthreads();                                         // barrier B

    #pragma unroll
    for (int qs = 0; qs < 2; ++qs) {
      int cq = qs * 16 + q16;
      float ct = reds[0][cq] + reds[1][cq] + reds[2][cq] + reds[3][cq];
      Sp[qs] = (mc == 0) ? ct : Sp[qs] * rfp[qs] + ct;
    }

    // ---- PV over this chunk ----
    if (mc > 0) {
      #pragma unroll
      for (int c4 = 0; c4 < 4; ++c4)
        #pragma unroll
        for (int qs = 0; qs < 2; ++qs) oacc[c4][qs] *= rfp[qs];
    }
    LOADVB(1)
    __builtin_amdgcn_s_setprio(1);
    #pragma unroll
    for (int kp = 0; kp < 4; ++kp) {
      PVMFMA(2 * kp, va0, va1, va2, va3)
      if (2 * kp + 2 < 8) LOADVA(2 * kp + 2)
      PVMFMA(2 * kp + 1, vb0, vb1, vb2, vb3)
      if (2 * kp + 3 < 8) LOADVB(2 * kp + 3)
    }
    __builtin_amdgcn_s_setprio(0);
  }

  // ---- epilogue: stage into PB (obuf[32 n][256 cv], stride PROW), 16B/lane block write ----
  __syncthreads();
  float rinv[2];
  #pragma unroll
  for (int qs = 0; qs < 2; ++qs) rinv[qs] = 1.0f / Sp[qs];
  #pragma unroll
  for (int c4 = 0; c4 < 4; ++c4)
    #pragma unroll
    for (int qs = 0; qs < 2; ++qs) {
      uint2 pk;
      pk.x = (unsigned)f2bf(oacc[c4][qs][0] * rinv[qs]) | ((unsigned)f2bf(oacc[c4][qs][1] * rinv[qs]) << 16);
      pk.y = (unsigned)f2bf(oacc[c4][qs][2] * rinv[qs]) | ((unsigned)f2bf(oacc[c4][qs][3] * rinv[qs]) << 16);
      *(uint2*)&PB[(qs * 16 + q16) * PROW + w * 64 + c4 * 16 + qt * 4] = pk;
    }
  __syncthreads();
  const size_t obase = (size_t)(b * 256 + bx * 2) * 4096;
  #pragma unroll
  for (int it = 0; it < 4; ++it) {
    int u = it * 256 + tid;      // 16B unit
    int so = u * 8;              // shorts
    int ntl = so >> 12;
    int rem = so & 4095;
    int ks = rem >> 9;
    int slot = (rem >> 3) & 63;
    int qq = slot & 15, cg = slot >> 4;
    uint4 val = *(const uint4*)&PB[(ntl * 16 + qq) * PROW + ks * 32 + cg * 8];
    *(uint4*)(oT + obase + so) = val;
  }
}

// ---------- final conv: FM A (oT) and FM W, XCD-local b ----------

__global__ __launch_bounds__(256)
void conv_final(const unsigned short* __restrict__ A, const unsigned short* __restrict__ W,
                const float* __restrict__ bias, float* __restrict__ out,
                const float* __restrict__ resid, const float* __restrict__ gamma_p)
{
  const int bid = blockIdx.x;
  const int b = bid & 7;
  const int idx = bid >> 3;
  const int n0 = (idx & 31) * 128;
  const int oc0 = (idx >> 5) * 128;
  const int tid = threadIdx.x, w = tid >> 6, lane = tid & 63, q = lane & 15, qt = lane >> 4;

  f32x4 acc[2][8];
  #pragma unroll
  for (int nt = 0; nt < 2; ++nt)
    #pragma unroll
    for (int ot = 0; ot < 8; ++ot) acc[nt][ot] = (f32x4){0.f, 0.f, 0.f, 0.f};

  #pragma unroll
  for (int ks = 0; ks < 8; ++ks) {
    bf16x8 A_[2], B_[8];
    #pragma unroll
    for (int nt = 0; nt < 2; ++nt)
      A_[nt] = *(const bf16x8*)(A + (((size_t)(b * 256 + (n0 >> 4) + w * 2 + nt) * 8 + ks) << 9) + lane * 8);
    #pragma unroll
    for (int ot = 0; ot < 8; ++ot)
      B_[ot] = *(const bf16x8*)(W + (((size_t)((oc0 >> 4) + ot) * 8 + ks) << 9) + lane * 8);
    #pragma unroll
    for (int nt = 0; nt < 2; ++nt)
      #pragma unroll
      for (int ot = 0; ot < 8; ++ot)
        acc[nt][ot] = MFMA16(A_[nt], B_[ot], acc[nt][ot]);
  }

  const float gm = gamma_p[0];
  #pragma unroll
  for (int ot = 0; ot < 8; ++ot) {
    int oc = oc0 + ot * 16 + q;
    float bs = bias[oc];
    #pragma unroll
    for (int nt = 0; nt < 2; ++nt) {
      int n = n0 + w * 32 + nt * 16 + qt * 4;
      size_t o = ((size_t)(b * 512) + oc) * 4096 + n;
      float4 rs = *(const float4*)&resid[o];
      float4 ov;
      ov.x = gm * (acc[nt][ot][0] + bs) + rs.x;
      ov.y = gm * (acc[nt][ot][1] + bs) + rs.y;
      ov.z = gm * (acc[nt][ot][2] + bs) + rs.z;
      ov.w = gm * (acc[nt][ot][3] + bs) + rs.w;
      *(float4*)&out[o] = ov;
    }
  }
}

// ---------- launch ----------

extern "C" void kernel_launch(void* const* d_in, const int* in_sizes, int n_in,
                              void* d_out, int out_size, void* d_ws, size_t ws_size,
                              hipStream_t stream) {
  const float* x     = (const float*)d_in[0];
  const float* Wf    = (const float*)d_in[1];
  const float* bf    = (const float*)d_in[2];
  const float* Wg    = (const float*)d_in[3];
  const float* bg    = (const float*)d_in[4];
  const float* Wh    = (const float*)d_in[5];
  const float* bh    = (const float*)d_in[6];
  const float* Wv    = (const float*)d_in[7];
  const float* bv    = (const float*)d_in[8];
  const float* gamma = (const float*)d_in[9];
  float* out = (float*)d_out;
  char* w = (char*)d_ws;

  unsigned short* fhi = (unsigned short*)(w);                 // 4 MB  FM [8][128][4][512]
  unsigned short* flo = (unsigned short*)(w + 4194304);       // 4 MB
  unsigned short* ghi = (unsigned short*)(w + 8388608);       // 1 MB  FM [8][32][4][512]
  unsigned short* glo = (unsigned short*)(w + 9437184);       // 1 MB
  unsigned short* vp  = (unsigned short*)(w + 10485760);      // 4 MB  FM [8][16][32][512]
  unsigned short* oT  = (unsigned short*)(w + 14680064);      // 16 MB FM [8][256][8][512]
  unsigned short* wfh = (unsigned short*)(w + 31457280);      // 64 KB FM
  unsigned short* wfl = (unsigned short*)(w + 31522816);
  unsigned short* wgh = (unsigned short*)(w + 31588352);
  unsigned short* wgl = (unsigned short*)(w + 31653888);
  unsigned short* whb = (unsigned short*)(w + 31719424);      // 256 KB FM
  unsigned short* wvb = (unsigned short*)(w + 31981568);      // 256 KB FM

  prep_k<<<1280, 256, 0, stream>>>(Wf, Wg, Wh, Wv, wfh, wfl, wgh, wgl, whb, wvb);

  conv_all<<<512, 256, 0, stream>>>(x, wfh, wfl, wgh, wgl, whb,
                                    bf, bg, bh, fhi, flo, ghi, glo, vp);

  attn_mfma<<<1024, 256, 0, stream>>>(fhi, flo, ghi, glo, vp, oT);

  conv_final<<<1024, 256, 0, stream>>>(oT, wvb, bv, out, x, gamma);
}

// Round 18
// 110.430 us; speedup vs baseline: 1.0565x; 1.0565x over previous
//
#include <hip/hip_runtime.h>
#include <cstddef>

typedef __attribute__((ext_vector_type(4))) float f32x4;
typedef __attribute__((ext_vector_type(16))) float f32x16;
typedef __attribute__((ext_vector_type(8))) short bf16x8;

#define MFMA16(A, B, C) __builtin_amdgcn_mfma_f32_16x16x32_bf16(A, B, C, 0, 0, 0)
#define MFMA32(A, B, C) __builtin_amdgcn_mfma_f32_32x32x16_bf16(A, B, C, 0, 0, 0)
#define AS1 __attribute__((address_space(1)))
#define AS3 __attribute__((address_space(3)))

__device__ __forceinline__ unsigned short f2bf(float f) {
  unsigned u = __float_as_uint(f);
  u += 0x7fffu + ((u >> 16) & 1u);
  return (unsigned short)(u >> 16);
}
__device__ __forceinline__ float bf2f(unsigned short s) {
  return __uint_as_float(((unsigned)s) << 16);
}

__device__ __forceinline__ void cvt_split8(float4 a, float4 b, bf16x8* H, bf16x8* L) {
  float v[8] = {a.x, a.y, a.z, a.w, b.x, b.y, b.z, b.w};
  unsigned hh[4], ll[4];
  #pragma unroll
  for (int p = 0; p < 4; ++p) {
    unsigned short h0 = f2bf(v[2 * p]), h1 = f2bf(v[2 * p + 1]);
    hh[p] = (unsigned)h0 | ((unsigned)h1 << 16);
    unsigned short l0 = f2bf(v[2 * p] - bf2f(h0));
    unsigned short l1 = f2bf(v[2 * p + 1] - bf2f(h1));
    ll[p] = (unsigned)l0 | ((unsigned)l1 << 16);
  }
  uint4 uh; uh.x = hh[0]; uh.y = hh[1]; uh.z = hh[2]; uh.w = hh[3];
  uint4 ul; ul.x = ll[0]; ul.y = ll[1]; ul.z = ll[2]; ul.w = ll[3];
  *H = *(bf16x8*)&uh;
  *L = *(bf16x8*)&ul;
}

__device__ __forceinline__ bf16x8 cvt_hi8(float4 a, float4 b) {
  float v[8] = {a.x, a.y, a.z, a.w, b.x, b.y, b.z, b.w};
  unsigned hh[4];
  #pragma unroll
  for (int p = 0; p < 4; ++p)
    hh[p] = (unsigned)f2bf(v[2 * p]) | ((unsigned)f2bf(v[2 * p + 1]) << 16);
  uint4 uh; uh.x = hh[0]; uh.y = hh[1]; uh.z = hh[2]; uh.w = hh[3];
  return *(bf16x8*)&uh;
}

// ---------- weight prep: fragment-major (FM) ----------

__global__ void prep_k(const float* __restrict__ Wf, const float* __restrict__ Wg,
                       const float* __restrict__ Wh, const float* __restrict__ Wv,
                       unsigned short* __restrict__ wfh, unsigned short* __restrict__ wfl,
                       unsigned short* __restrict__ wgh, unsigned short* __restrict__ wgl,
                       unsigned short* __restrict__ whb, unsigned short* __restrict__ wvb) {
  int i = blockIdx.x * 256 + threadIdx.x;
  if (i < 65536) {
    int ii = i & 32767;
    int j = ii & 7, slot = (ii >> 3) & 63, q = slot & 15, qt2 = slot >> 4;
    int kt = (ii >> 9) & 15, oct = ii >> 13;
    const float* src = (i < 32768) ? Wf : Wg;
    unsigned short* dh = (i < 32768) ? wfh : wgh;
    unsigned short* dl = (i < 32768) ? wfl : wgl;
    float v = src[(oct * 16 + q) * 512 + kt * 32 + qt2 * 8 + j];
    unsigned short h = f2bf(v);
    dh[ii] = h; dl[ii] = f2bf(v - bf2f(h));
  } else if (i < 196608) {
    int ii = i - 65536;
    int j = ii & 7, slot = (ii >> 3) & 63, q = slot & 15, qt2 = slot >> 4;
    int kt = (ii >> 9) & 15, oct = ii >> 13;
    whb[ii] = f2bf(Wh[(oct * 16 + q) * 512 + kt * 32 + qt2 * 8 + j]);
  } else if (i < 327680) {
    int ii = i - 196608;
    int j = ii & 7, slot = (ii >> 3) & 63, q = slot & 15, qt2 = slot >> 4;
    int kt = (ii >> 9) & 7, oct = ii >> 12;
    wvb[ii] = f2bf(Wv[(oct * 16 + q) * 256 + kt * 32 + qt2 * 8 + j]);
  }
}

// ---------- conv_all: K-chunk 32, LDS-shared weights + x via global_load_lds ----------
// smem layout (64 KB): xs buf0 [32][128] f32 @0, buf1 @16K; w buf0 (16 frags x 1KB) @32K, buf1 @48K.
// Role 0: f+g split (weight slots 0-3 wfh, 4-7 wfl, 8-11 wgh, 12-15 wgl).
// Role 1: v 256oc (slots oc16 = 0..15 of whb).

#define STAGEX(XP, CN) { _Pragma("unroll") \
  for (int c_ = 0; c_ < 4; ++c_) \
    __builtin_amdgcn_global_load_lds( \
      (const AS1 unsigned int*)(xg + (size_t)((CN) * 32 + c_ * 2) * 4096), \
      (AS3 unsigned int*)((XP) + (w * 8 + c_ * 2) * 128), 16, 0, 0); }

#define STAGEW0(WP, CN) { \
  const unsigned short* Wt_ = (w == 0) ? wfh_ : (w == 1) ? wfl_ : (w == 2) ? wgh_ : wgl_; \
  _Pragma("unroll") \
  for (int ot_ = 0; ot_ < 4; ++ot_) \
    __builtin_amdgcn_global_load_lds( \
      (const AS1 unsigned int*)(Wt_ + (((size_t)(ot_ * 16 + (CN))) << 9) + lane * 8), \
      (AS3 unsigned int*)((WP) + (w * 4 + ot_) * 512), 16, 0, 0); }

#define STAGEW1(WP, CN) { _Pragma("unroll") \
  for (int i_ = 0; i_ < 4; ++i_) \
    __builtin_amdgcn_global_load_lds( \
      (const AS1 unsigned int*)(whb_ + (((size_t)((w * 4 + i_) * 16 + (CN))) << 9) + lane * 8), \
      (AS3 unsigned int*)((WP) + (w * 4 + i_) * 512), 16, 0, 0); }

__global__ __launch_bounds__(256, 2)
void conv_all(const float* __restrict__ x,
              const unsigned short* __restrict__ wfh_, const unsigned short* __restrict__ wfl_,
              const unsigned short* __restrict__ wgh_, const unsigned short* __restrict__ wgl_,
              const unsigned short* __restrict__ whb_,
              const float* __restrict__ bf_, const float* __restrict__ bg_,
              const float* __restrict__ bh_,
              unsigned short* __restrict__ fhi, unsigned short* __restrict__ flo,
              unsigned short* __restrict__ ghi, unsigned short* __restrict__ glo,
              unsigned short* __restrict__ vp)
{
  __shared__ __align__(16) char smem[65536];
  float* xs0 = (float*)smem;                               // [32][128]
  float* xs1 = (float*)(smem + 16384);
  unsigned short* ws0 = (unsigned short*)(smem + 32768);   // 16 x 512 shorts
  unsigned short* ws1 = (unsigned short*)(smem + 49152);
  const int bid = blockIdx.x;
  const int b = bid & 7;
  const int idx = bid >> 3;
  const int role = idx & 1;
  const int hp = idx >> 1;
  const int n0 = hp * 128;
  const int tid = threadIdx.x, w = tid >> 6, lane = tid & 63, q = lane & 15, qt = lane >> 4;
  const float* xg = x + ((size_t)(b * 512 + w * 8 + (lane >> 5)) * 4096) + n0 + (lane & 31) * 4;

  if (role == 0) {
    f32x4 accf[2][4], accg[2][4];
    #pragma unroll
    for (int nt = 0; nt < 2; ++nt)
      #pragma unroll
      for (int ot = 0; ot < 4; ++ot) {
        accf[nt][ot] = (f32x4){0.f, 0.f, 0.f, 0.f};
        accg[nt][ot] = (f32x4){0.f, 0.f, 0.f, 0.f};
      }
    STAGEX(xs0, 0) STAGEW0(ws0, 0)
    __syncthreads();
    for (int cc = 0; cc < 16; ++cc) {
      const float* xsp = (cc & 1) ? xs1 : xs0;
      const unsigned short* wp = (cc & 1) ? ws1 : ws0;
      float* xsn = (cc & 1) ? xs0 : xs1;
      unsigned short* wn = (cc & 1) ? ws0 : ws1;
      if (cc < 15) { STAGEX(xsn, cc + 1) STAGEW0(wn, cc + 1) }
      bf16x8 Ah[2], Al[2];
      #pragma unroll
      for (int nt = 0; nt < 2; ++nt) {
        const int row = w * 32 + nt * 16 + q;
        float xv[8];
        #pragma unroll
        for (int j = 0; j < 8; ++j)
          xv[j] = xsp[(qt * 8 + j) * 128 + row];
        float4 a0; a0.x = xv[0]; a0.y = xv[1]; a0.z = xv[2]; a0.w = xv[3];
        float4 a1; a1.x = xv[4]; a1.y = xv[5]; a1.z = xv[6]; a1.w = xv[7];
        cvt_split8(a0, a1, &Ah[nt], &Al[nt]);
      }
      {
        bf16x8 Bh[4], Bl[4];
        #pragma unroll
        for (int ot = 0; ot < 4; ++ot) {
          Bh[ot] = *(const bf16x8*)&wp[(0 + ot) * 512 + lane * 8];
          Bl[ot] = *(const bf16x8*)&wp[(4 + ot) * 512 + lane * 8];
        }
        #pragma unroll
        for (int nt = 0; nt < 2; ++nt)
          #pragma unroll
          for (int ot = 0; ot < 4; ++ot) {
            accf[nt][ot] = MFMA16(Ah[nt], Bh[ot], accf[nt][ot]);
            accf[nt][ot] = MFMA16(Ah[nt], Bl[ot], accf[nt][ot]);
            accf[nt][ot] = MFMA16(Al[nt], Bh[ot], accf[nt][ot]);
          }
      }
      {
        bf16x8 Bh[4], Bl[4];
        #pragma unroll
        for (int ot = 0; ot < 4; ++ot) {
          Bh[ot] = *(const bf16x8*)&wp[(8 + ot) * 512 + lane * 8];
          Bl[ot] = *(const bf16x8*)&wp[(12 + ot) * 512 + lane * 8];
        }
        #pragma unroll
        for (int nt = 0; nt < 2; ++nt)
          #pragma unroll
          for (int ot = 0; ot < 4; ++ot) {
            accg[nt][ot] = MFMA16(Ah[nt], Bh[ot], accg[nt][ot]);
            accg[nt][ot] = MFMA16(Ah[nt], Bl[ot], accg[nt][ot]);
            accg[nt][ot] = MFMA16(Al[nt], Bh[ot], accg[nt][ot]);
          }
      }
      __syncthreads();
    }
    // f epilogue: FM for attn MFMA32-B
    #pragma unroll
    for (int nt = 0; nt < 2; ++nt)
      #pragma unroll
      for (int ot = 0; ot < 4; ++ot)
        #pragma unroll
        for (int r = 0; r < 4; ++r) {
          float v = accf[nt][ot][r] + bf_[ot * 16 + q];
          unsigned short h = f2bf(v);
          size_t o = (((size_t)(b * 128 + hp * 4 + w) * 4 + ot) * 64 +
                      (q >> 3) * 32 + nt * 16 + qt * 4 + r) * 8 + (q & 7);
          fhi[o] = h;
          flo[o] = f2bf(v - bf2f(h));
        }
    // g epilogue: pool via LDS -> FM for attn MFMA32-A
    float (*pl)[67] = (float(*)[67])smem;
    #pragma unroll
    for (int nt = 0; nt < 2; ++nt)
      #pragma unroll
      for (int ot = 0; ot < 4; ++ot)
        #pragma unroll
        for (int r = 0; r < 4; ++r)
          pl[w * 32 + nt * 16 + qt * 4 + r][ot * 16 + q] = accg[nt][ot][r];
    __syncthreads();
    const int c = tid & 63;
    #pragma unroll
    for (int it = 0; it < 8; ++it) {
      int wp2 = (tid >> 6) + it * 4;
      float v = fmaxf(fmaxf(pl[2 * wp2][c], pl[2 * wp2 + 1][c]),
                      fmaxf(pl[64 + 2 * wp2][c], pl[65 + 2 * wp2][c])) + bg_[c];
      unsigned short h = f2bf(v);
      size_t o = (((size_t)(b * 32 + hp) * 4 + (c >> 4)) * 64 +
                  ((c >> 3) & 1) * 32 + wp2) * 8 + (c & 7);
      ghi[o] = h;
      glo[o] = f2bf(v - bf2f(h));
    }
  } else {
    f32x4 acc[2][16];
    #pragma unroll
    for (int nt = 0; nt < 2; ++nt)
      #pragma unroll
      for (int ot = 0; ot < 16; ++ot) acc[nt][ot] = (f32x4){0.f, 0.f, 0.f, 0.f};
    STAGEX(xs0, 0) STAGEW1(ws0, 0)
    __syncthreads();
    for (int cc = 0; cc < 16; ++cc) {
      const float* xsp = (cc & 1) ? xs1 : xs0;
      const unsigned short* wp = (cc & 1) ? ws1 : ws0;
      float* xsn = (cc & 1) ? xs0 : xs1;
      unsigned short* wn = (cc & 1) ? ws0 : ws1;
      if (cc < 15) { STAGEX(xsn, cc + 1) STAGEW1(wn, cc + 1) }
      bf16x8 A_[2];
      #pragma unroll
      for (int nt = 0; nt < 2; ++nt) {
        const int row = w * 32 + nt * 16 + q;
        float xv[8];
        #pragma unroll
        for (int j = 0; j < 8; ++j)
          xv[j] = xsp[(qt * 8 + j) * 128 + row];
        float4 a0; a0.x = xv[0]; a0.y = xv[1]; a0.z = xv[2]; a0.w = xv[3];
        float4 a1; a1.x = xv[4]; a1.y = xv[5]; a1.z = xv[6]; a1.w = xv[7];
        A_[nt] = cvt_hi8(a0, a1);
      }
      #pragma unroll
      for (int oh = 0; oh < 2; ++oh) {
        bf16x8 B_[8];
        #pragma unroll
        for (int ot = 0; ot < 8; ++ot)
          B_[ot] = *(const bf16x8*)&wp[(oh * 8 + ot) * 512 + lane * 8];
        #pragma unroll
        for (int nt = 0; nt < 2; ++nt)
          #pragma unroll
          for (int ot = 0; ot < 8; ++ot)
            acc[nt][oh * 8 + ot] = MFMA16(A_[nt], B_[ot], acc[nt][oh * 8 + ot]);
      }
      __syncthreads();
    }
    float (*pl)[67] = (float(*)[67])smem;
    #pragma unroll
    for (int oh = 0; oh < 4; ++oh) {
      if (oh) __syncthreads();
      #pragma unroll
      for (int nt = 0; nt < 2; ++nt)
        #pragma unroll
        for (int ot4 = 0; ot4 < 4; ++ot4)
          #pragma unroll
          for (int r = 0; r < 4; ++r)
            pl[w * 32 + nt * 16 + qt * 4 + r][ot4 * 16 + q] = acc[nt][oh * 4 + ot4][r];
      __syncthreads();
      const int wp2 = tid & 31;
      #pragma unroll
      for (int it = 0; it < 8; ++it) {
        int cc2 = (tid >> 5) + it * 8;
        int cv = oh * 64 + cc2;
        float v = fmaxf(fmaxf(pl[2 * wp2][cc2], pl[2 * wp2 + 1][cc2]),
                        fmaxf(pl[64 + 2 * wp2][cc2], pl[65 + 2 * wp2][cc2])) + bh_[cv];
        size_t o = (((size_t)(b * 16 + (cv >> 4)) * 32 + hp) * 64 +
                    (wp2 >> 3) * 16 + (cv & 15)) * 8 + (wp2 & 7);
        vp[o] = f2bf(v);
      }
    }
  }
}

// ---------- fused attention: QB=64, 4 m-chunks, per-thread (M,S), 2 barriers/chunk ----------

#define PROW 264

__global__ __launch_bounds__(256, 2)
void attn_mfma(const unsigned short* __restrict__ f_, const unsigned short* __restrict__ fl_,
               const unsigned short* __restrict__ g_, const unsigned short* __restrict__ gl_,
               const unsigned short* __restrict__ vp, unsigned short* __restrict__ oT)
{
  __shared__ __align__(16) unsigned short PB[64 * PROW];
  __shared__ float redm[4][2][32], reds[4][2][32];
  const int b = blockIdx.x & 7, bx = blockIdx.x >> 3;
  const int tid = threadIdx.x, w = tid >> 6, lane = tid & 63;
  const int q32 = lane & 31, hl = lane >> 5;
  const int q16 = lane & 15, qt = lane >> 4;

  bf16x8 Fh[2][4], Fl[2][4];
  #pragma unroll
  for (int qt2 = 0; qt2 < 2; ++qt2) {
    size_t fb = ((size_t)(b * 128 + bx * 2 + qt2) << 11) + lane * 8;
    #pragma unroll
    for (int s = 0; s < 4; ++s) {
      Fh[qt2][s] = *(const bf16x8*)(f_ + fb + (s << 9));
      Fl[qt2][s] = *(const bf16x8*)(fl_ + fb + (s << 9));
    }
  }

  float M0 = -3.0e38f, M1 = -3.0e38f;
  float Mp[4], Sp[4];
  #pragma unroll
  for (int qs = 0; qs < 4; ++qs) { Mp[qs] = -3.0e38f; Sp[qs] = 0.f; }
  f32x4 oacc[4][4];
  #pragma unroll
  for (int c4 = 0; c4 < 4; ++c4)
    #pragma unroll
    for (int qs = 0; qs < 4; ++qs) oacc[c4][qs] = (f32x4){0.f, 0.f, 0.f, 0.f};
  const size_t vroot = ((size_t)(b * 16 + w * 4) * 32) * 512 + lane * 8;

#define VLD(C4, KS) (*(const bf16x8*)(vp + vroot + ((size_t)((C4) * 32 + mc * 8 + (KS)) << 9)))
#define LOADVA(KS) { va0 = VLD(0, KS); va1 = VLD(1, KS); va2 = VLD(2, KS); va3 = VLD(3, KS); }
#define LOADVB(KS) { vb0 = VLD(0, KS); vb1 = VLD(1, KS); vb2 = VLD(2, KS); vb3 = VLD(3, KS); }
#define PVMFMA(KS, V0, V1, V2, V3) { \
  bf16x8 pb0 = *(const bf16x8*)&PB[q16 * PROW + (KS) * 32 + qt * 8]; \
  bf16x8 pb1 = *(const bf16x8*)&PB[(16 + q16) * PROW + (KS) * 32 + qt * 8]; \
  bf16x8 pb2 = *(const bf16x8*)&PB[(32 + q16) * PROW + (KS) * 32 + qt * 8]; \
  bf16x8 pb3 = *(const bf16x8*)&PB[(48 + q16) * PROW + (KS) * 32 + qt * 8]; \
  oacc[0][0] = MFMA16(V0, pb0, oacc[0][0]); oacc[1][0] = MFMA16(V1, pb0, oacc[1][0]); \
  oacc[2][0] = MFMA16(V2, pb0, oacc[2][0]); oacc[3][0] = MFMA16(V3, pb0, oacc[3][0]); \
  oacc[0][1] = MFMA16(V0, pb1, oacc[0][1]); oacc[1][1] = MFMA16(V1, pb1, oacc[1][1]); \
  oacc[2][1] = MFMA16(V2, pb1, oacc[2][1]); oacc[3][1] = MFMA16(V3, pb1, oacc[3][1]); \
  oacc[0][2] = MFMA16(V0, pb2, oacc[0][2]); oacc[1][2] = MFMA16(V1, pb2, oacc[1][2]); \
  oacc[2][2] = MFMA16(V2, pb2, oacc[2][2]); oacc[3][2] = MFMA16(V3, pb2, oacc[3][2]); \
  oacc[0][3] = MFMA16(V0, pb3, oacc[0][3]); oacc[1][3] = MFMA16(V1, pb3, oacc[1][3]); \
  oacc[2][3] = MFMA16(V2, pb3, oacc[2][3]); oacc[3][3] = MFMA16(V3, pb3, oacc[3][3]); }

  #pragma unroll 1
  for (int mc = 0; mc < 4; ++mc) {
    f32x16 sa0t0 = {}, sa0t1 = {}, sa1t0 = {}, sa1t1 = {};
    __builtin_amdgcn_s_setprio(1);
    #pragma unroll
    for (int t = 0; t < 2; ++t) {
      size_t gb = ((size_t)(b * 32 + mc * 8 + w * 2 + t) << 11) + lane * 8;
      bf16x8 Gh[4], Gl[4];
      #pragma unroll
      for (int s = 0; s < 4; ++s) {
        Gh[s] = *(const bf16x8*)(g_ + gb + (s << 9));
        Gl[s] = *(const bf16x8*)(gl_ + gb + (s << 9));
      }
      f32x16* s0 = t ? &sa0t1 : &sa0t0;
      f32x16* s1 = t ? &sa1t1 : &sa1t0;
      #pragma unroll
      for (int s = 0; s < 4; ++s) {
        *s0 = MFMA32(Gh[s], Fh[0][s], *s0);
        *s0 = MFMA32(Gh[s], Fl[0][s], *s0);
        *s0 = MFMA32(Gl[s], Fh[0][s], *s0);
        *s1 = MFMA32(Gh[s], Fh[1][s], *s1);
        *s1 = MFMA32(Gh[s], Fl[1][s], *s1);
        *s1 = MFMA32(Gl[s], Fh[1][s], *s1);
      }
    }
    __builtin_amdgcn_s_setprio(0);

    bf16x8 va0, va1, va2, va3, vb0, vb1, vb2, vb3;
    LOADVA(0)

    float mx0 = -3.0e38f, mx1 = -3.0e38f;
    #pragma unroll
    for (int r = 0; r < 16; ++r) {
      mx0 = fmaxf(mx0, fmaxf(sa0t0[r], sa0t1[r]));
      mx1 = fmaxf(mx1, fmaxf(sa1t0[r], sa1t1[r]));
    }
    mx0 = fmaxf(mx0, __shfl_xor(mx0, 32));
    mx1 = fmaxf(mx1, __shfl_xor(mx1, 32));
    if (lane < 32) { redm[w][0][lane] = mx0; redm[w][1][lane] = mx1; }
    __syncthreads();
    float gmx0 = fmaxf(fmaxf(redm[0][0][q32], redm[1][0][q32]), fmaxf(redm[2][0][q32], redm[3][0][q32]));
    float gmx1 = fmaxf(fmaxf(redm[0][1][q32], redm[1][1][q32]), fmaxf(redm[2][1][q32], redm[3][1][q32]));
    float Mn0 = fmaxf(M0, gmx0), Mn1 = fmaxf(M1, gmx1);
    M0 = Mn0; M1 = Mn1;

    float rfp[4];
    #pragma unroll
    for (int qs = 0; qs < 4; ++qs) {
      int hq = qs >> 1, cq = (qs & 1) * 16 + q16;
      float gm = fmaxf(fmaxf(redm[0][hq][cq], redm[1][hq][cq]),
                       fmaxf(redm[2][hq][cq], redm[3][hq][cq]));
      float Mn = fmaxf(Mp[qs], gm);
      rfp[qs] = __expf(Mp[qs] - Mn);
      Mp[qs] = Mn;
    }

    float cs0 = 0.f, cs1 = 0.f;
    #pragma unroll
    for (int r = 0; r < 16; ++r) {
      float p;
      p = __expf(sa0t0[r] - Mn0); sa0t0[r] = p; cs0 += p;
      p = __expf(sa0t1[r] - Mn0); sa0t1[r] = p; cs0 += p;
      p = __expf(sa1t0[r] - Mn1); sa1t0[r] = p; cs1 += p;
      p = __expf(sa1t1[r] - Mn1); sa1t1[r] = p; cs1 += p;
    }
    cs0 += __shfl_xor(cs0, 32);
    cs1 += __shfl_xor(cs1, 32);
    if (lane < 32) { reds[w][0][lane] = cs0; reds[w][1][lane] = cs1; }

    #pragma unroll
    for (int j = 0; j < 4; ++j) {
      uint2 pk;
      pk.x = (unsigned)f2bf(sa0t0[4*j+0]) | ((unsigned)f2bf(sa0t0[4*j+1]) << 16);
      pk.y = (unsigned)f2bf(sa0t0[4*j+2]) | ((unsigned)f2bf(sa0t0[4*j+3]) << 16);
      *(uint2*)&PB[q32 * PROW + w * 64 + j * 8 + hl * 4] = pk;
      pk.x = (unsigned)f2bf(sa0t1[4*j+0]) | ((unsigned)f2bf(sa0t1[4*j+1]) << 16);
      pk.y = (unsigned)f2bf(sa0t1[4*j+2]) | ((unsigned)f2bf(sa0t1[4*j+3]) << 16);
      *(uint2*)&PB[q32 * PROW + w * 64 + 32 + j * 8 + hl * 4] = pk;
      pk.x = (unsigned)f2bf(sa1t0[4*j+0]) | ((unsigned)f2bf(sa1t0[4*j+1]) << 16);
      pk.y = (unsigned)f2bf(sa1t0[4*j+2]) | ((unsigned)f2bf(sa1t0[4*j+3]) << 16);
      *(uint2*)&PB[(32 + q32) * PROW + w * 64 + j * 8 + hl * 4] = pk;
      pk.x = (unsigned)f2bf(sa1t1[4*j+0]) | ((unsigned)f2bf(sa1t1[4*j+1]) << 16);
      pk.y = (unsigned)f2bf(sa1t1[4*j+2]) | ((unsigned)f2bf(sa1t1[4*j+3]) << 16);
      *(uint2*)&PB[(32 + q32) * PROW + w * 64 + 32 + j * 8 + hl * 4] = pk;
    }
    __syncthreads();

    #pragma unroll
    for (int qs = 0; qs < 4; ++qs) {
      int hq = qs >> 1, cq = (qs & 1) * 16 + q16;
      float ct = reds[0][hq][cq] + reds[1][hq][cq] + reds[2][hq][cq] + reds[3][hq][cq];
      Sp[qs] = (mc == 0) ? ct : Sp[qs] * rfp[qs] + ct;
    }

    if (mc > 0) {
      #pragma unroll
      for (int c4 = 0; c4 < 4; ++c4)
        #pragma unroll
        for (int qs = 0; qs < 4; ++qs) oacc[c4][qs] *= rfp[qs];
    }
    LOADVB(1)
    __builtin_amdgcn_s_setprio(1);
    #pragma unroll
    for (int kp = 0; kp < 4; ++kp) {
      PVMFMA(2 * kp, va0, va1, va2, va3)
      if (2 * kp + 2 < 8) LOADVA(2 * kp + 2)
      PVMFMA(2 * kp + 1, vb0, vb1, vb2, vb3)
      if (2 * kp + 3 < 8) LOADVB(2 * kp + 3)
    }
    __builtin_amdgcn_s_setprio(0);
  }

  __syncthreads();
  float rinv[4];
  #pragma unroll
  for (int qs = 0; qs < 4; ++qs) rinv[qs] = 1.0f / Sp[qs];
  #pragma unroll
  for (int c4 = 0; c4 < 4; ++c4)
    #pragma unroll
    for (int qs = 0; qs < 4; ++qs) {
      uint2 pk;
      pk.x = (unsigned)f2bf(oacc[c4][qs][0] * rinv[qs]) | ((unsigned)f2bf(oacc[c4][qs][1] * rinv[qs]) << 16);
      pk.y = (unsigned)f2bf(oacc[c4][qs][2] * rinv[qs]) | ((unsigned)f2bf(oacc[c4][qs][3] * rinv[qs]) << 16);
      *(uint2*)&PB[(qs * 16 + q16) * PROW + w * 64 + c4 * 16 + qt * 4] = pk;
    }
  __syncthreads();
  const size_t obase = (size_t)(b * 256 + bx * 4) * 4096;
  #pragma unroll
  for (int it = 0; it < 8; ++it) {
    int u = it * 256 + tid;
    int so = u * 8;
    int ntl = so >> 12;
    int rem = so & 4095;
    int ks = rem >> 9;
    int slot = (rem >> 3) & 63;
    int qq = slot & 15, cg = slot >> 4;
    uint4 val = *(const uint4*)&PB[(ntl * 16 + qq) * PROW + ks * 32 + cg * 8];
    *(uint4*)(oT + obase + so) = val;
  }
}

// ---------- final conv: FM A (oT) and FM W, XCD-local b ----------

__global__ __launch_bounds__(256)
void conv_final(const unsigned short* __restrict__ A, const unsigned short* __restrict__ W,
                const float* __restrict__ bias, float* __restrict__ out,
                const float* __restrict__ resid, const float* __restrict__ gamma_p)
{
  const int bid = blockIdx.x;
  const int b = bid & 7;
  const int idx = bid >> 3;
  const int n0 = (idx & 31) * 128;
  const int oc0 = (idx >> 5) * 128;
  const int tid = threadIdx.x, w = tid >> 6, lane = tid & 63, q = lane & 15, qt = lane >> 4;

  f32x4 acc[2][8];
  #pragma unroll
  for (int nt = 0; nt < 2; ++nt)
    #pragma unroll
    for (int ot = 0; ot < 8; ++ot) acc[nt][ot] = (f32x4){0.f, 0.f, 0.f, 0.f};

  #pragma unroll
  for (int ks = 0; ks < 8; ++ks) {
    bf16x8 A_[2], B_[8];
    #pragma unroll
    for (int nt = 0; nt < 2; ++nt)
      A_[nt] = *(const bf16x8*)(A + (((size_t)(b * 256 + (n0 >> 4) + w * 2 + nt) * 8 + ks) << 9) + lane * 8);
    #pragma unroll
    for (int ot = 0; ot < 8; ++ot)
      B_[ot] = *(const bf16x8*)(W + (((size_t)((oc0 >> 4) + ot) * 8 + ks) << 9) + lane * 8);
    #pragma unroll
    for (int nt = 0; nt < 2; ++nt)
      #pragma unroll
      for (int ot = 0; ot < 8; ++ot)
        acc[nt][ot] = MFMA16(A_[nt], B_[ot], acc[nt][ot]);
  }

  const float gm = gamma_p[0];
  #pragma unroll
  for (int ot = 0; ot < 8; ++ot) {
    int oc = oc0 + ot * 16 + q;
    float bs = bias[oc];
    #pragma unroll
    for (int nt = 0; nt < 2; ++nt) {
      int n = n0 + w * 32 + nt * 16 + qt * 4;
      size_t o = ((size_t)(b * 512) + oc) * 4096 + n;
      float4 rs = *(const float4*)&resid[o];
      float4 ov;
      ov.x = gm * (acc[nt][ot][0] + bs) + rs.x;
      ov.y = gm * (acc[nt][ot][1] + bs) + rs.y;
      ov.z = gm * (acc[nt][ot][2] + bs) + rs.z;
      ov.w = gm * (acc[nt][ot][3] + bs) + rs.w;
      *(float4*)&out[o] = ov;
    }
  }
}

// ---------- launch ----------

extern "C" void kernel_launch(void* const* d_in, const int* in_sizes, int n_in,
                              void* d_out, int out_size, void* d_ws, size_t ws_size,
                              hipStream_t stream) {
  const float* x     = (const float*)d_in[0];
  const float* Wf    = (const float*)d_in[1];
  const float* bf    = (const float*)d_in[2];
  const float* Wg    = (const float*)d_in[3];
  const float* bg    = (const float*)d_in[4];
  const float* Wh    = (const float*)d_in[5];
  const float* bh    = (const float*)d_in[6];
  const float* Wv    = (const float*)d_in[7];
  const float* bv    = (const float*)d_in[8];
  const float* gamma = (const float*)d_in[9];
  float* out = (float*)d_out;
  char* w = (char*)d_ws;

  unsigned short* fhi = (unsigned short*)(w);                 // 4 MB  FM [8][128][4][512]
  unsigned short* flo = (unsigned short*)(w + 4194304);       // 4 MB
  unsigned short* ghi = (unsigned short*)(w + 8388608);       // 1 MB  FM [8][32][4][512]
  unsigned short* glo = (unsigned short*)(w + 9437184);       // 1 MB
  unsigned short* vp  = (unsigned short*)(w + 10485760);      // 4 MB  FM [8][16][32][512]
  unsigned short* oT  = (unsigned short*)(w + 14680064);      // 16 MB FM [8][256][8][512]
  unsigned short* wfh = (unsigned short*)(w + 31457280);      // 64 KB FM
  unsigned short* wfl = (unsigned short*)(w + 31522816);
  unsigned short* wgh = (unsigned short*)(w + 31588352);
  unsigned short* wgl = (unsigned short*)(w + 31653888);
  unsigned short* whb = (unsigned short*)(w + 31719424);      // 256 KB FM
  unsigned short* wvb = (unsigned short*)(w + 31981568);      // 256 KB FM

  prep_k<<<1280, 256, 0, stream>>>(Wf, Wg, Wh, Wv, wfh, wfl, wgh, wgl, whb, wvb);

  conv_all<<<512, 256, 0, stream>>>(x, wfh, wfl, wgh, wgl, whb,
                                    bf, bg, bh, fhi, flo, ghi, glo, vp);

  attn_mfma<<<512, 256, 0, stream>>>(fhi, flo, ghi, glo, vp, oT);

  conv_final<<<1024, 256, 0, stream>>>(oT, wvb, bv, out, x, gamma);
}

// Round 19
// 100.503 us; speedup vs baseline: 1.1608x; 1.0988x over previous
//
#include <hip/hip_runtime.h>
#include <cstddef>

typedef __attribute__((ext_vector_type(4))) float f32x4;
typedef __attribute__((ext_vector_type(16))) float f32x16;
typedef __attribute__((ext_vector_type(8))) short bf16x8;

#define MFMA16(A, B, C) __builtin_amdgcn_mfma_f32_16x16x32_bf16(A, B, C, 0, 0, 0)
#define MFMA32(A, B, C) __builtin_amdgcn_mfma_f32_32x32x16_bf16(A, B, C, 0, 0, 0)
#define AS1 __attribute__((address_space(1)))
#define AS3 __attribute__((address_space(3)))

__device__ __forceinline__ unsigned short f2bf(float f) {
  unsigned u = __float_as_uint(f);
  u += 0x7fffu + ((u >> 16) & 1u);
  return (unsigned short)(u >> 16);
}
__device__ __forceinline__ float bf2f(unsigned short s) {
  return __uint_as_float(((unsigned)s) << 16);
}

__device__ __forceinline__ void cvt_split8(float4 a, float4 b, bf16x8* H, bf16x8* L) {
  float v[8] = {a.x, a.y, a.z, a.w, b.x, b.y, b.z, b.w};
  unsigned hh[4], ll[4];
  #pragma unroll
  for (int p = 0; p < 4; ++p) {
    unsigned short h0 = f2bf(v[2 * p]), h1 = f2bf(v[2 * p + 1]);
    hh[p] = (unsigned)h0 | ((unsigned)h1 << 16);
    unsigned short l0 = f2bf(v[2 * p] - bf2f(h0));
    unsigned short l1 = f2bf(v[2 * p + 1] - bf2f(h1));
    ll[p] = (unsigned)l0 | ((unsigned)l1 << 16);
  }
  uint4 uh; uh.x = hh[0]; uh.y = hh[1]; uh.z = hh[2]; uh.w = hh[3];
  uint4 ul; ul.x = ll[0]; ul.y = ll[1]; ul.z = ll[2]; ul.w = ll[3];
  *H = *(bf16x8*)&uh;
  *L = *(bf16x8*)&ul;
}

__device__ __forceinline__ bf16x8 cvt_hi8(float4 a, float4 b) {
  float v[8] = {a.x, a.y, a.z, a.w, b.x, b.y, b.z, b.w};
  unsigned hh[4];
  #pragma unroll
  for (int p = 0; p < 4; ++p)
    hh[p] = (unsigned)f2bf(v[2 * p]) | ((unsigned)f2bf(v[2 * p + 1]) << 16);
  uint4 uh; uh.x = hh[0]; uh.y = hh[1]; uh.z = hh[2]; uh.w = hh[3];
  return *(bf16x8*)&uh;
}

// ---------- weight prep: fragment-major (FM) ----------

__global__ void prep_k(const float* __restrict__ Wf, const float* __restrict__ Wg,
                       const float* __restrict__ Wh, const float* __restrict__ Wv,
                       unsigned short* __restrict__ wfh, unsigned short* __restrict__ wfl,
                       unsigned short* __restrict__ wgh, unsigned short* __restrict__ wgl,
                       unsigned short* __restrict__ whb, unsigned short* __restrict__ wvb) {
  int i = blockIdx.x * 256 + threadIdx.x;
  if (i < 65536) {
    int ii = i & 32767;
    int j = ii & 7, slot = (ii >> 3) & 63, q = slot & 15, qt2 = slot >> 4;
    int kt = (ii >> 9) & 15, oct = ii >> 13;
    const float* src = (i < 32768) ? Wf : Wg;
    unsigned short* dh = (i < 32768) ? wfh : wgh;
    unsigned short* dl = (i < 32768) ? wfl : wgl;
    float v = src[(oct * 16 + q) * 512 + kt * 32 + qt2 * 8 + j];
    unsigned short h = f2bf(v);
    dh[ii] = h; dl[ii] = f2bf(v - bf2f(h));
  } else if (i < 196608) {
    int ii = i - 65536;
    int j = ii & 7, slot = (ii >> 3) & 63, q = slot & 15, qt2 = slot >> 4;
    int kt = (ii >> 9) & 15, oct = ii >> 13;
    whb[ii] = f2bf(Wh[(oct * 16 + q) * 512 + kt * 32 + qt2 * 8 + j]);
  } else if (i < 327680) {
    int ii = i - 196608;
    int j = ii & 7, slot = (ii >> 3) & 63, q = slot & 15, qt2 = slot >> 4;
    int kt = (ii >> 9) & 7, oct = ii >> 12;
    wvb[ii] = f2bf(Wv[(oct * 16 + q) * 256 + kt * 32 + qt2 * 8 + j]);
  }
}

// ---------- conv_all (R18 verbatim): K-chunk 32, LDS-shared weights + x via global_load_lds ----------

#define STAGEX(XP, CN) { _Pragma("unroll") \
  for (int c_ = 0; c_ < 4; ++c_) \
    __builtin_amdgcn_global_load_lds( \
      (const AS1 unsigned int*)(xg + (size_t)((CN) * 32 + c_ * 2) * 4096), \
      (AS3 unsigned int*)((XP) + (w * 8 + c_ * 2) * 128), 16, 0, 0); }

#define STAGEW0(WP, CN) { \
  const unsigned short* Wt_ = (w == 0) ? wfh_ : (w == 1) ? wfl_ : (w == 2) ? wgh_ : wgl_; \
  _Pragma("unroll") \
  for (int ot_ = 0; ot_ < 4; ++ot_) \
    __builtin_amdgcn_global_load_lds( \
      (const AS1 unsigned int*)(Wt_ + (((size_t)(ot_ * 16 + (CN))) << 9) + lane * 8), \
      (AS3 unsigned int*)((WP) + (w * 4 + ot_) * 512), 16, 0, 0); }

#define STAGEW1(WP, CN) { _Pragma("unroll") \
  for (int i_ = 0; i_ < 4; ++i_) \
    __builtin_amdgcn_global_load_lds( \
      (const AS1 unsigned int*)(whb_ + (((size_t)((w * 4 + i_) * 16 + (CN))) << 9) + lane * 8), \
      (AS3 unsigned int*)((WP) + (w * 4 + i_) * 512), 16, 0, 0); }

__global__ __launch_bounds__(256, 2)
void conv_all(const float* __restrict__ x,
              const unsigned short* __restrict__ wfh_, const unsigned short* __restrict__ wfl_,
              const unsigned short* __restrict__ wgh_, const unsigned short* __restrict__ wgl_,
              const unsigned short* __restrict__ whb_,
              const float* __restrict__ bf_, const float* __restrict__ bg_,
              const float* __restrict__ bh_,
              unsigned short* __restrict__ fhi, unsigned short* __restrict__ flo,
              unsigned short* __restrict__ ghi, unsigned short* __restrict__ glo,
              unsigned short* __restrict__ vp)
{
  __shared__ __align__(16) char smem[65536];
  float* xs0 = (float*)smem;
  float* xs1 = (float*)(smem + 16384);
  unsigned short* ws0 = (unsigned short*)(smem + 32768);
  unsigned short* ws1 = (unsigned short*)(smem + 49152);
  const int bid = blockIdx.x;
  const int b = bid & 7;
  const int idx = bid >> 3;
  const int role = idx & 1;
  const int hp = idx >> 1;
  const int n0 = hp * 128;
  const int tid = threadIdx.x, w = tid >> 6, lane = tid & 63, q = lane & 15, qt = lane >> 4;
  const float* xg = x + ((size_t)(b * 512 + w * 8 + (lane >> 5)) * 4096) + n0 + (lane & 31) * 4;

  if (role == 0) {
    f32x4 accf[2][4], accg[2][4];
    #pragma unroll
    for (int nt = 0; nt < 2; ++nt)
      #pragma unroll
      for (int ot = 0; ot < 4; ++ot) {
        accf[nt][ot] = (f32x4){0.f, 0.f, 0.f, 0.f};
        accg[nt][ot] = (f32x4){0.f, 0.f, 0.f, 0.f};
      }
    STAGEX(xs0, 0) STAGEW0(ws0, 0)
    __syncthreads();
    for (int cc = 0; cc < 16; ++cc) {
      const float* xsp = (cc & 1) ? xs1 : xs0;
      const unsigned short* wp = (cc & 1) ? ws1 : ws0;
      float* xsn = (cc & 1) ? xs0 : xs1;
      unsigned short* wn = (cc & 1) ? ws0 : ws1;
      if (cc < 15) { STAGEX(xsn, cc + 1) STAGEW0(wn, cc + 1) }
      bf16x8 Ah[2], Al[2];
      #pragma unroll
      for (int nt = 0; nt < 2; ++nt) {
        const int row = w * 32 + nt * 16 + q;
        float xv[8];
        #pragma unroll
        for (int j = 0; j < 8; ++j)
          xv[j] = xsp[(qt * 8 + j) * 128 + row];
        float4 a0; a0.x = xv[0]; a0.y = xv[1]; a0.z = xv[2]; a0.w = xv[3];
        float4 a1; a1.x = xv[4]; a1.y = xv[5]; a1.z = xv[6]; a1.w = xv[7];
        cvt_split8(a0, a1, &Ah[nt], &Al[nt]);
      }
      {
        bf16x8 Bh[4], Bl[4];
        #pragma unroll
        for (int ot = 0; ot < 4; ++ot) {
          Bh[ot] = *(const bf16x8*)&wp[(0 + ot) * 512 + lane * 8];
          Bl[ot] = *(const bf16x8*)&wp[(4 + ot) * 512 + lane * 8];
        }
        #pragma unroll
        for (int nt = 0; nt < 2; ++nt)
          #pragma unroll
          for (int ot = 0; ot < 4; ++ot) {
            accf[nt][ot] = MFMA16(Ah[nt], Bh[ot], accf[nt][ot]);
            accf[nt][ot] = MFMA16(Ah[nt], Bl[ot], accf[nt][ot]);
            accf[nt][ot] = MFMA16(Al[nt], Bh[ot], accf[nt][ot]);
          }
      }
      {
        bf16x8 Bh[4], Bl[4];
        #pragma unroll
        for (int ot = 0; ot < 4; ++ot) {
          Bh[ot] = *(const bf16x8*)&wp[(8 + ot) * 512 + lane * 8];
          Bl[ot] = *(const bf16x8*)&wp[(12 + ot) * 512 + lane * 8];
        }
        #pragma unroll
        for (int nt = 0; nt < 2; ++nt)
          #pragma unroll
          for (int ot = 0; ot < 4; ++ot) {
            accg[nt][ot] = MFMA16(Ah[nt], Bh[ot], accg[nt][ot]);
            accg[nt][ot] = MFMA16(Ah[nt], Bl[ot], accg[nt][ot]);
            accg[nt][ot] = MFMA16(Al[nt], Bh[ot], accg[nt][ot]);
          }
      }
      __syncthreads();
    }
    #pragma unroll
    for (int nt = 0; nt < 2; ++nt)
      #pragma unroll
      for (int ot = 0; ot < 4; ++ot)
        #pragma unroll
        for (int r = 0; r < 4; ++r) {
          float v = accf[nt][ot][r] + bf_[ot * 16 + q];
          unsigned short h = f2bf(v);
          size_t o = (((size_t)(b * 128 + hp * 4 + w) * 4 + ot) * 64 +
                      (q >> 3) * 32 + nt * 16 + qt * 4 + r) * 8 + (q & 7);
          fhi[o] = h;
          flo[o] = f2bf(v - bf2f(h));
        }
    float (*pl)[67] = (float(*)[67])smem;
    #pragma unroll
    for (int nt = 0; nt < 2; ++nt)
      #pragma unroll
      for (int ot = 0; ot < 4; ++ot)
        #pragma unroll
        for (int r = 0; r < 4; ++r)
          pl[w * 32 + nt * 16 + qt * 4 + r][ot * 16 + q] = accg[nt][ot][r];
    __syncthreads();
    const int c = tid & 63;
    #pragma unroll
    for (int it = 0; it < 8; ++it) {
      int wp2 = (tid >> 6) + it * 4;
      float v = fmaxf(fmaxf(pl[2 * wp2][c], pl[2 * wp2 + 1][c]),
                      fmaxf(pl[64 + 2 * wp2][c], pl[65 + 2 * wp2][c])) + bg_[c];
      unsigned short h = f2bf(v);
      size_t o = (((size_t)(b * 32 + hp) * 4 + (c >> 4)) * 64 +
                  ((c >> 3) & 1) * 32 + wp2) * 8 + (c & 7);
      ghi[o] = h;
      glo[o] = f2bf(v - bf2f(h));
    }
  } else {
    f32x4 acc[2][16];
    #pragma unroll
    for (int nt = 0; nt < 2; ++nt)
      #pragma unroll
      for (int ot = 0; ot < 16; ++ot) acc[nt][ot] = (f32x4){0.f, 0.f, 0.f, 0.f};
    STAGEX(xs0, 0) STAGEW1(ws0, 0)
    __syncthreads();
    for (int cc = 0; cc < 16; ++cc) {
      const float* xsp = (cc & 1) ? xs1 : xs0;
      const unsigned short* wp = (cc & 1) ? ws1 : ws0;
      float* xsn = (cc & 1) ? xs0 : xs1;
      unsigned short* wn = (cc & 1) ? ws0 : ws1;
      if (cc < 15) { STAGEX(xsn, cc + 1) STAGEW1(wn, cc + 1) }
      bf16x8 A_[2];
      #pragma unroll
      for (int nt = 0; nt < 2; ++nt) {
        const int row = w * 32 + nt * 16 + q;
        float xv[8];
        #pragma unroll
        for (int j = 0; j < 8; ++j)
          xv[j] = xsp[(qt * 8 + j) * 128 + row];
        float4 a0; a0.x = xv[0]; a0.y = xv[1]; a0.z = xv[2]; a0.w = xv[3];
        float4 a1; a1.x = xv[4]; a1.y = xv[5]; a1.z = xv[6]; a1.w = xv[7];
        A_[nt] = cvt_hi8(a0, a1);
      }
      #pragma unroll
      for (int oh = 0; oh < 2; ++oh) {
        bf16x8 B_[8];
        #pragma unroll
        for (int ot = 0; ot < 8; ++ot)
          B_[ot] = *(const bf16x8*)&wp[(oh * 8 + ot) * 512 + lane * 8];
        #pragma unroll
        for (int nt = 0; nt < 2; ++nt)
          #pragma unroll
          for (int ot = 0; ot < 8; ++ot)
            acc[nt][oh * 8 + ot] = MFMA16(A_[nt], B_[ot], acc[nt][oh * 8 + ot]);
      }
      __syncthreads();
    }
    float (*pl)[67] = (float(*)[67])smem;
    #pragma unroll
    for (int oh = 0; oh < 4; ++oh) {
      if (oh) __syncthreads();
      #pragma unroll
      for (int nt = 0; nt < 2; ++nt)
        #pragma unroll
        for (int ot4 = 0; ot4 < 4; ++ot4)
          #pragma unroll
          for (int r = 0; r < 4; ++r)
            pl[w * 32 + nt * 16 + qt * 4 + r][ot4 * 16 + q] = acc[nt][oh * 4 + ot4][r];
      __syncthreads();
      const int wp2 = tid & 31;
      #pragma unroll
      for (int it = 0; it < 8; ++it) {
        int cc2 = (tid >> 5) + it * 8;
        int cv = oh * 64 + cc2;
        float v = fmaxf(fmaxf(pl[2 * wp2][cc2], pl[2 * wp2 + 1][cc2]),
                        fmaxf(pl[64 + 2 * wp2][cc2], pl[65 + 2 * wp2][cc2])) + bh_[cv];
        size_t o = (((size_t)(b * 16 + (cv >> 4)) * 32 + hp) * 64 +
                    (wp2 >> 3) * 16 + (cv & 15)) * 8 + (wp2 & 7);
        vp[o] = f2bf(v);
      }
    }
  }
}

// ---------- fused attention + final conv: QB=64, 4 m-chunks, fused Wv epilogue ----------

#define PROW 264

__global__ __launch_bounds__(256, 2)
void attn_mfma(const unsigned short* __restrict__ f_, const unsigned short* __restrict__ fl_,
               const unsigned short* __restrict__ g_, const unsigned short* __restrict__ gl_,
               const unsigned short* __restrict__ vp, const unsigned short* __restrict__ wv_,
               const float* __restrict__ bv_, const float* __restrict__ resid,
               const float* __restrict__ gamma_p, float* __restrict__ out)
{
  __shared__ __align__(16) unsigned short PB[64 * PROW];    // 33,792 B (P, then o FM frags)
  __shared__ float redm[4][2][32], reds[4][2][32];
  const int b = blockIdx.x & 7, bx = blockIdx.x >> 3;
  const int tid = threadIdx.x, w = tid >> 6, lane = tid & 63;
  const int q32 = lane & 31, hl = lane >> 5;
  const int q16 = lane & 15, qt = lane >> 4;

  bf16x8 Fh[2][4], Fl[2][4];
  #pragma unroll
  for (int qt2 = 0; qt2 < 2; ++qt2) {
    size_t fb = ((size_t)(b * 128 + bx * 2 + qt2) << 11) + lane * 8;
    #pragma unroll
    for (int s = 0; s < 4; ++s) {
      Fh[qt2][s] = *(const bf16x8*)(f_ + fb + (s << 9));
      Fl[qt2][s] = *(const bf16x8*)(fl_ + fb + (s << 9));
    }
  }

  float M0 = -3.0e38f, M1 = -3.0e38f;
  float Mp[4], Sp[4];
  #pragma unroll
  for (int qs = 0; qs < 4; ++qs) { Mp[qs] = -3.0e38f; Sp[qs] = 0.f; }
  f32x4 oacc[4][4];
  #pragma unroll
  for (int c4 = 0; c4 < 4; ++c4)
    #pragma unroll
    for (int qs = 0; qs < 4; ++qs) oacc[c4][qs] = (f32x4){0.f, 0.f, 0.f, 0.f};
  const size_t vroot = ((size_t)(b * 16 + w * 4) * 32) * 512 + lane * 8;

#define VLD(C4, KS) (*(const bf16x8*)(vp + vroot + ((size_t)((C4) * 32 + mc * 8 + (KS)) << 9)))
#define LOADVA(KS) { va0 = VLD(0, KS); va1 = VLD(1, KS); va2 = VLD(2, KS); va3 = VLD(3, KS); }
#define LOADVB(KS) { vb0 = VLD(0, KS); vb1 = VLD(1, KS); vb2 = VLD(2, KS); vb3 = VLD(3, KS); }
#define PVMFMA(KS, V0, V1, V2, V3) { \
  bf16x8 pb0 = *(const bf16x8*)&PB[q16 * PROW + (KS) * 32 + qt * 8]; \
  bf16x8 pb1 = *(const bf16x8*)&PB[(16 + q16) * PROW + (KS) * 32 + qt * 8]; \
  bf16x8 pb2 = *(const bf16x8*)&PB[(32 + q16) * PROW + (KS) * 32 + qt * 8]; \
  bf16x8 pb3 = *(const bf16x8*)&PB[(48 + q16) * PROW + (KS) * 32 + qt * 8]; \
  oacc[0][0] = MFMA16(V0, pb0, oacc[0][0]); oacc[1][0] = MFMA16(V1, pb0, oacc[1][0]); \
  oacc[2][0] = MFMA16(V2, pb0, oacc[2][0]); oacc[3][0] = MFMA16(V3, pb0, oacc[3][0]); \
  oacc[0][1] = MFMA16(V0, pb1, oacc[0][1]); oacc[1][1] = MFMA16(V1, pb1, oacc[1][1]); \
  oacc[2][1] = MFMA16(V2, pb1, oacc[2][1]); oacc[3][1] = MFMA16(V3, pb1, oacc[3][1]); \
  oacc[0][2] = MFMA16(V0, pb2, oacc[0][2]); oacc[1][2] = MFMA16(V1, pb2, oacc[1][2]); \
  oacc[2][2] = MFMA16(V2, pb2, oacc[2][2]); oacc[3][2] = MFMA16(V3, pb2, oacc[3][2]); \
  oacc[0][3] = MFMA16(V0, pb3, oacc[0][3]); oacc[1][3] = MFMA16(V1, pb3, oacc[1][3]); \
  oacc[2][3] = MFMA16(V2, pb3, oacc[2][3]); oacc[3][3] = MFMA16(V3, pb3, oacc[3][3]); }

  #pragma unroll 1
  for (int mc = 0; mc < 4; ++mc) {
    f32x16 sa0t0 = {}, sa0t1 = {}, sa1t0 = {}, sa1t1 = {};
    __builtin_amdgcn_s_setprio(1);
    #pragma unroll
    for (int t = 0; t < 2; ++t) {
      size_t gb = ((size_t)(b * 32 + mc * 8 + w * 2 + t) << 11) + lane * 8;
      bf16x8 Gh[4], Gl[4];
      #pragma unroll
      for (int s = 0; s < 4; ++s) {
        Gh[s] = *(const bf16x8*)(g_ + gb + (s << 9));
        Gl[s] = *(const bf16x8*)(gl_ + gb + (s << 9));
      }
      f32x16* s0 = t ? &sa0t1 : &sa0t0;
      f32x16* s1 = t ? &sa1t1 : &sa1t0;
      #pragma unroll
      for (int s = 0; s < 4; ++s) {
        *s0 = MFMA32(Gh[s], Fh[0][s], *s0);
        *s0 = MFMA32(Gh[s], Fl[0][s], *s0);
        *s0 = MFMA32(Gl[s], Fh[0][s], *s0);
        *s1 = MFMA32(Gh[s], Fh[1][s], *s1);
        *s1 = MFMA32(Gh[s], Fl[1][s], *s1);
        *s1 = MFMA32(Gl[s], Fh[1][s], *s1);
      }
    }
    __builtin_amdgcn_s_setprio(0);

    bf16x8 va0, va1, va2, va3, vb0, vb1, vb2, vb3;
    LOADVA(0)

    float mx0 = -3.0e38f, mx1 = -3.0e38f;
    #pragma unroll
    for (int r = 0; r < 16; ++r) {
      mx0 = fmaxf(mx0, fmaxf(sa0t0[r], sa0t1[r]));
      mx1 = fmaxf(mx1, fmaxf(sa1t0[r], sa1t1[r]));
    }
    mx0 = fmaxf(mx0, __shfl_xor(mx0, 32));
    mx1 = fmaxf(mx1, __shfl_xor(mx1, 32));
    if (lane < 32) { redm[w][0][lane] = mx0; redm[w][1][lane] = mx1; }
    __syncthreads();
    float gmx0 = fmaxf(fmaxf(redm[0][0][q32], redm[1][0][q32]), fmaxf(redm[2][0][q32], redm[3][0][q32]));
    float gmx1 = fmaxf(fmaxf(redm[0][1][q32], redm[1][1][q32]), fmaxf(redm[2][1][q32], redm[3][1][q32]));
    float Mn0 = fmaxf(M0, gmx0), Mn1 = fmaxf(M1, gmx1);
    M0 = Mn0; M1 = Mn1;

    float rfp[4];
    #pragma unroll
    for (int qs = 0; qs < 4; ++qs) {
      int hq = qs >> 1, cq = (qs & 1) * 16 + q16;
      float gm2 = fmaxf(fmaxf(redm[0][hq][cq], redm[1][hq][cq]),
                        fmaxf(redm[2][hq][cq], redm[3][hq][cq]));
      float Mn = fmaxf(Mp[qs], gm2);
      rfp[qs] = __expf(Mp[qs] - Mn);
      Mp[qs] = Mn;
    }

    float cs0 = 0.f, cs1 = 0.f;
    #pragma unroll
    for (int r = 0; r < 16; ++r) {
      float p;
      p = __expf(sa0t0[r] - Mn0); sa0t0[r] = p; cs0 += p;
      p = __expf(sa0t1[r] - Mn0); sa0t1[r] = p; cs0 += p;
      p = __expf(sa1t0[r] - Mn1); sa1t0[r] = p; cs1 += p;
      p = __expf(sa1t1[r] - Mn1); sa1t1[r] = p; cs1 += p;
    }
    cs0 += __shfl_xor(cs0, 32);
    cs1 += __shfl_xor(cs1, 32);
    if (lane < 32) { reds[w][0][lane] = cs0; reds[w][1][lane] = cs1; }

    #pragma unroll
    for (int j = 0; j < 4; ++j) {
      uint2 pk;
      pk.x = (unsigned)f2bf(sa0t0[4*j+0]) | ((unsigned)f2bf(sa0t0[4*j+1]) << 16);
      pk.y = (unsigned)f2bf(sa0t0[4*j+2]) | ((unsigned)f2bf(sa0t0[4*j+3]) << 16);
      *(uint2*)&PB[q32 * PROW + w * 64 + j * 8 + hl * 4] = pk;
      pk.x = (unsigned)f2bf(sa0t1[4*j+0]) | ((unsigned)f2bf(sa0t1[4*j+1]) << 16);
      pk.y = (unsigned)f2bf(sa0t1[4*j+2]) | ((unsigned)f2bf(sa0t1[4*j+3]) << 16);
      *(uint2*)&PB[q32 * PROW + w * 64 + 32 + j * 8 + hl * 4] = pk;
      pk.x = (unsigned)f2bf(sa1t0[4*j+0]) | ((unsigned)f2bf(sa1t0[4*j+1]) << 16);
      pk.y = (unsigned)f2bf(sa1t0[4*j+2]) | ((unsigned)f2bf(sa1t0[4*j+3]) << 16);
      *(uint2*)&PB[(32 + q32) * PROW + w * 64 + j * 8 + hl * 4] = pk;
      pk.x = (unsigned)f2bf(sa1t1[4*j+0]) | ((unsigned)f2bf(sa1t1[4*j+1]) << 16);
      pk.y = (unsigned)f2bf(sa1t1[4*j+2]) | ((unsigned)f2bf(sa1t1[4*j+3]) << 16);
      *(uint2*)&PB[(32 + q32) * PROW + w * 64 + 32 + j * 8 + hl * 4] = pk;
    }
    __syncthreads();

    #pragma unroll
    for (int qs = 0; qs < 4; ++qs) {
      int hq = qs >> 1, cq = (qs & 1) * 16 + q16;
      float ct = reds[0][hq][cq] + reds[1][hq][cq] + reds[2][hq][cq] + reds[3][hq][cq];
      Sp[qs] = (mc == 0) ? ct : Sp[qs] * rfp[qs] + ct;
    }

    if (mc > 0) {
      #pragma unroll
      for (int c4 = 0; c4 < 4; ++c4)
        #pragma unroll
        for (int qs = 0; qs < 4; ++qs) oacc[c4][qs] *= rfp[qs];
    }
    LOADVB(1)
    __builtin_amdgcn_s_setprio(1);
    #pragma unroll
    for (int kp = 0; kp < 4; ++kp) {
      PVMFMA(2 * kp, va0, va1, va2, va3)
      if (2 * kp + 2 < 8) LOADVA(2 * kp + 2)
      PVMFMA(2 * kp + 1, vb0, vb1, vb2, vb3)
      if (2 * kp + 3 < 8) LOADVB(2 * kp + 3)
    }
    __builtin_amdgcn_s_setprio(0);
  }

  // ---- fused final conv epilogue ----
  // Stage o into PB as FM fragments: frag (nt=qs, ks), slot = sub*16+q16, elem.
  __syncthreads();
  float rinv[4];
  #pragma unroll
  for (int qs = 0; qs < 4; ++qs) rinv[qs] = 1.0f / Sp[qs];
  #pragma unroll
  for (int c4 = 0; c4 < 4; ++c4)
    #pragma unroll
    for (int qs = 0; qs < 4; ++qs) {
      uint2 pk;
      pk.x = (unsigned)f2bf(oacc[c4][qs][0] * rinv[qs]) | ((unsigned)f2bf(oacc[c4][qs][1] * rinv[qs]) << 16);
      pk.y = (unsigned)f2bf(oacc[c4][qs][2] * rinv[qs]) | ((unsigned)f2bf(oacc[c4][qs][3] * rinv[qs]) << 16);
      int cv = w * 64 + c4 * 16 + qt * 4;
      int ks = cv >> 5;
      int sub = (cv & 31) >> 3;
      int off = (((qs * 8 + ks) * 64 + sub * 16 + q16) << 3) + (qt & 1) * 4;
      *(uint2*)&PB[off] = pk;
    }
  __syncthreads();
  const float gm = gamma_p[0];
  const int nbase = bx * 64;
  #pragma unroll
  for (int oh = 0; oh < 2; ++oh) {
    f32x4 acc2[4][4];   // [nt][ot]
    #pragma unroll
    for (int nt = 0; nt < 4; ++nt)
      #pragma unroll
      for (int ot = 0; ot < 4; ++ot) acc2[nt][ot] = (f32x4){0.f, 0.f, 0.f, 0.f};
    #pragma unroll
    for (int ks = 0; ks < 8; ++ks) {
      bf16x8 A_[4], B_[4];
      #pragma unroll
      for (int nt = 0; nt < 4; ++nt)
        A_[nt] = *(const bf16x8*)&PB[((nt * 8 + ks) * 64 + lane) * 8];
      #pragma unroll
      for (int ot = 0; ot < 4; ++ot) {
        int octile = w * 8 + oh * 4 + ot;
        B_[ot] = *(const bf16x8*)(wv_ + (((size_t)(octile * 8 + ks)) << 9) + lane * 8);
      }
      #pragma unroll
      for (int nt = 0; nt < 4; ++nt)
        #pragma unroll
        for (int ot = 0; ot < 4; ++ot)
          acc2[nt][ot] = MFMA16(A_[nt], B_[ot], acc2[nt][ot]);
    }
    #pragma unroll
    for (int ot = 0; ot < 4; ++ot) {
      int oc = (w * 8 + oh * 4 + ot) * 16 + q16;
      float bs = bv_[oc];
      #pragma unroll
      for (int nt = 0; nt < 4; ++nt) {
        int n = nbase + nt * 16 + qt * 4;
        size_t o = ((size_t)(b * 512) + oc) * 4096 + n;
        float4 rs = *(const float4*)&resid[o];
        float4 ov;
        ov.x = gm * (acc2[nt][ot][0] + bs) + rs.x;
        ov.y = gm * (acc2[nt][ot][1] + bs) + rs.y;
        ov.z = gm * (acc2[nt][ot][2] + bs) + rs.z;
        ov.w = gm * (acc2[nt][ot][3] + bs) + rs.w;
        *(float4*)&out[o] = ov;
      }
    }
  }
}

// ---------- launch ----------

extern "C" void kernel_launch(void* const* d_in, const int* in_sizes, int n_in,
                              void* d_out, int out_size, void* d_ws, size_t ws_size,
                              hipStream_t stream) {
  const float* x     = (const float*)d_in[0];
  const float* Wf    = (const float*)d_in[1];
  const float* bf    = (const float*)d_in[2];
  const float* Wg    = (const float*)d_in[3];
  const float* bg    = (const float*)d_in[4];
  const float* Wh    = (const float*)d_in[5];
  const float* bh    = (const float*)d_in[6];
  const float* Wv    = (const float*)d_in[7];
  const float* bv    = (const float*)d_in[8];
  const float* gamma = (const float*)d_in[9];
  float* out = (float*)d_out;
  char* w = (char*)d_ws;

  unsigned short* fhi = (unsigned short*)(w);                 // 4 MB  FM [8][128][4][512]
  unsigned short* flo = (unsigned short*)(w + 4194304);       // 4 MB
  unsigned short* ghi = (unsigned short*)(w + 8388608);       // 1 MB  FM [8][32][4][512]
  unsigned short* glo = (unsigned short*)(w + 9437184);       // 1 MB
  unsigned short* vp  = (unsigned short*)(w + 10485760);      // 4 MB  FM [8][16][32][512]
  unsigned short* wfh = (unsigned short*)(w + 14680064);      // 64 KB FM
  unsigned short* wfl = (unsigned short*)(w + 14745600);
  unsigned short* wgh = (unsigned short*)(w + 14811136);
  unsigned short* wgl = (unsigned short*)(w + 14876672);
  unsigned short* whb = (unsigned short*)(w + 14942208);      // 256 KB FM
  unsigned short* wvb = (unsigned short*)(w + 15204352);      // 256 KB FM

  prep_k<<<1280, 256, 0, stream>>>(Wf, Wg, Wh, Wv, wfh, wfl, wgh, wgl, whb, wvb);

  conv_all<<<512, 256, 0, stream>>>(x, wfh, wfl, wgh, wgl, whb,
                                    bf, bg, bh, fhi, flo, ghi, glo, vp);

  attn_mfma<<<512, 256, 0, stream>>>(fhi, flo, ghi, glo, vp, wvb, bv, x, gamma, out);
}